// Round 14
// baseline (378.956 us; speedup 1.0000x reference)
//
#include <hip/hip_runtime.h>
#include <hip/hip_bf16.h>

// GraphAttentionEmbedding: 2-layer TransformerConv GNN on MI355X.
// Round 14: serial-overhead reduction. Decoupled-lookback single-pass scan
// (replaces 3 scan kernels); ef_gather re-laid to 4 threads/row (uint4
// writes, half the redundant se reads). Agg/GEMM kernels unchanged (agg1f
// measured at ~2.9TB/s random-gather fetch = practical floor).

typedef unsigned int  u32;
typedef unsigned short u16;
typedef __attribute__((ext_vector_type(8))) __bf16 bf16x8;
typedef __attribute__((ext_vector_type(4))) float  f32x4;

#define S1L (0.17677669529663687f * 1.4426950408889634f)  // 1/sqrt(32)*log2(e)
#define S2L (0.125f * 1.4426950408889634f)                // 1/sqrt(64)*log2(e)

__device__ __forceinline__ u16 f2bf(float f) {
    u32 u = __float_as_uint(f);
    u32 r = (u + 0x7fffu + ((u >> 16) & 1u)) >> 16;   // round-nearest-even
    return (u16)r;
}
__device__ __forceinline__ float bflo(u32 u) { return __uint_as_float(u << 16); }
__device__ __forceinline__ float bfhi(u32 u) { return __uint_as_float(u & 0xffff0000u); }

template<int CTRL>
__device__ __forceinline__ float dpp_add(float x) {
    int y = __builtin_amdgcn_mov_dpp(__float_as_int(x), CTRL, 0xF, 0xF, true);
    return x + __int_as_float(y);
}

// ------------------------------------------------------------- CSR build
__global__ void k_hist(const int* __restrict__ dst, int* __restrict__ deg, int nE) {
    int e = blockIdx.x * 256 + threadIdx.x;
    if (e < nE) atomicAdd(&deg[dst[e]], 1);
}

// single-pass scan with decoupled lookback; all blocks co-resident (<=1024).
__global__ __launch_bounds__(1024) void k_scan_lb(
    const int* __restrict__ deg, int* __restrict__ rp, int* __restrict__ fill,
    int* __restrict__ partials, int* __restrict__ flags,
    int* __restrict__ rowptr, int nN, int nE)
{
    __shared__ int buf[1024];
    __shared__ int carry_s;
    const int b = blockIdx.x, tid = threadIdx.x, idx = b * 1024 + tid;
    int v = (idx < nN) ? deg[idx] : 0;
    buf[tid] = v;
    __syncthreads();
    for (int off = 1; off < 1024; off <<= 1) {
        int t = (tid >= off) ? buf[tid - off] : 0;
        __syncthreads();
        buf[tid] += t;
        __syncthreads();
    }
    const int incl = buf[tid];
    if (tid == 1023) {
        partials[b] = incl;          // block total
        __threadfence();
        atomicExch(&flags[b], 1);
        int c = 0;
        for (int j = b - 1; j >= 0; --j) {
            while (atomicAdd(&flags[j], 0) == 0) { }
            c += atomicAdd(&partials[j], 0);
        }
        carry_s = c;
    }
    __syncthreads();
    if (idx < nN) {
        int r = carry_s + incl - v;
        rp[idx] = r;
        fill[idx] = r;
    }
    if (b == 0 && tid == 0) rowptr[nN] = nE;
}

// ------------- merged: permutation scatter + weight transposes + x->bf16
__global__ void k_scatter_prep(
    const int* __restrict__ src, const int* __restrict__ dst,
    int* __restrict__ fill, int2* __restrict__ se, int nE,
    const float* __restrict__ Wq1, const float* __restrict__ Wk1,
    const float* __restrict__ Wv1, const float* __restrict__ Ws1,
    const float* __restrict__ Wq2, const float* __restrict__ Wk2,
    const float* __restrict__ Wv2, const float* __restrict__ Ws2,
    const float* __restrict__ We1, const float* __restrict__ We2,
    const float* __restrict__ bq1, const float* __restrict__ bq2,
    u16* __restrict__ WB1, u16* __restrict__ WB2,
    float* __restrict__ bqe1, float* __restrict__ bqe2,
    const float4* __restrict__ x4, uint2* __restrict__ xb4, int nN)
{
    long g = (long)blockIdx.x * 256 + threadIdx.x;
    if (g < nE) {               // permutation scatter
        int e = (int)g;
        int p = atomicAdd(&fill[dst[e]], 1);
        se[p] = make_int2(src[e], e);
        return;
    }
    long t = g - nE;
    if (t < 65536) {            // WB1 main: 512 cols x 128 k
        int j = (int)t >> 7, k = (int)t & 127;
        int m = j >> 7, col = j & 127;
        const float* W = (m == 0) ? Wq1 : (m == 1) ? Wk1 : (m == 2) ? Wv1 : Ws1;
        WB1[t] = f2bf(W[k * 128 + col]);
        return;
    }
    t -= 65536;
    if (t < 49152) {            // WB2 main: 384 cols x 128 k (with pad)
        int j = (int)t >> 7, k = (int)t & 127;
        if (j < 256) {
            int m = j >> 6, col = j & 63;
            const float* W = (m == 0) ? Wq2 : (m == 1) ? Wk2 : (m == 2) ? Wv2 : Ws2;
            WB2[t] = f2bf(W[k * 64 + col]);
        } else if (j >= 288) {
            WB2[t] = 0;
        }
        return;
    }
    t -= 49152;
    if (t < 16384) {            // WqE1 -> WB1 cols 512..639
        int j = (int)t >> 7, m = (int)t & 127;
        int h = j >> 5, c = j & 31;
        float acc = 0.f;
        #pragma unroll
        for (int d = 0; d < 32; ++d)
            acc += Wq1[m * 128 + h * 32 + d] * We1[c * 128 + h * 32 + d];
        WB1[512 * 128 + j * 128 + m] = f2bf(acc * S1L);
        if (m == 0) {
            float b = 0.f;
            #pragma unroll
            for (int d = 0; d < 32; ++d)
                b += bq1[h * 32 + d] * We1[c * 128 + h * 32 + d];
            bqe1[j] = b * S1L;
        }
        return;
    }
    t -= 16384;
    if (t < 4096) {             // WqE2 -> WB2 cols 256..287
        int c = (int)t >> 7, m = (int)t & 127;
        float acc = 0.f;
        #pragma unroll
        for (int d = 0; d < 64; ++d)
            acc += Wq2[m * 64 + d] * We2[c * 64 + d];
        WB2[256 * 128 + c * 128 + m] = f2bf(acc * S2L);
        if (m == 0) {
            float b = 0.f;
            #pragma unroll
            for (int d = 0; d < 64; ++d) b += bq2[d] * We2[c * 64 + d];
            bqe2[c] = b * S2L;
        }
        return;
    }
    t -= 4096;
    if (t < (long)nN * 32) {    // x -> bf16
        float4 f = x4[t];
        xb4[t] = make_uint2((u32)f2bf(f.x) | ((u32)f2bf(f.y) << 16),
                            (u32)f2bf(f.z) | ((u32)f2bf(f.w) << 16));
    }
}

// gather+convert edge features into CSR order; 4 threads/row, uint4 writes
__global__ void k_ef_gather(const int2* __restrict__ se, const float4* __restrict__ ef4,
                            uint4* __restrict__ efc4, int nE)
{
    int t = blockIdx.x * 256 + threadIdx.x;
    int p = t >> 2, sub = t & 3;
    if (p >= nE) return;
    int e = se[p].y;
    float4 a = ef4[(size_t)e * 8 + sub * 2];
    float4 b = ef4[(size_t)e * 8 + sub * 2 + 1];
    efc4[(size_t)p * 4 + sub] =
        make_uint4((u32)f2bf(a.x) | ((u32)f2bf(a.y) << 16),
                   (u32)f2bf(a.z) | ((u32)f2bf(a.w) << 16),
                   (u32)f2bf(b.x) | ((u32)f2bf(b.y) << 16),
                   (u32)f2bf(b.z) | ((u32)f2bf(b.w) << 16));
}

// ------------------------------------------- 128x128-tile MFMA GEMM, layer 1
__global__ __launch_bounds__(256) void k_lin_gemm1(
    const u16* __restrict__ xb, const u16* __restrict__ WB,
    const float* __restrict__ bq, const float* __restrict__ bk,
    const float* __restrict__ bv, const float* __restrict__ bs,
    const float* __restrict__ bqe,
    u32* __restrict__ qqe1, u32* __restrict__ kv1, float* __restrict__ sk1, int nN)
{
    __shared__ __align__(16) u16 lds[2 * 128 * 128];   // 64 KB
    const int tid = threadIdx.x;
    const int ct = blockIdx.y;
    const int rowbase = blockIdx.x * 128;

    {
        const int lr = tid >> 4, kc = tid & 15;
        #pragma unroll
        for (int it = 0; it < 8; ++it) {
            int row = it * 16 + lr;
            int grow = rowbase + row; if (grow >= nN) grow = nN - 1;
            uint4 va = *(const uint4*)(xb + (size_t)grow * 128 + kc * 8);
            *(uint4*)((char*)lds + row * 256 + ((kc * 16) ^ ((row & 7) << 4))) = va;
        }
        #pragma unroll
        for (int it = 0; it < 8; ++it) {
            int row = it * 16 + lr;
            uint4 vb = *(const uint4*)(WB + ((size_t)ct * 128 + row) * 128 + kc * 8);
            *(uint4*)((char*)lds + 32768 + row * 256 + ((kc * 16) ^ ((row & 7) << 4))) = vb;
        }
    }
    __syncthreads();

    const int wave = tid >> 6, lane = tid & 63;
    const int wr = wave >> 1, wc = wave & 1;
    const int colL = lane & 15, kgrp = lane >> 4;

    f32x4 acc[4][4];
    #pragma unroll
    for (int m = 0; m < 4; ++m)
        #pragma unroll
        for (int n = 0; n < 4; ++n) acc[m][n] = {0.f, 0.f, 0.f, 0.f};

    #pragma unroll
    for (int ks = 0; ks < 4; ++ks) {
        const int kb = ks * 64 + kgrp * 16;
        bf16x8 af[4], bfr[4];
        #pragma unroll
        for (int m = 0; m < 4; ++m) {
            int row = wr * 64 + m * 16 + colL;
            af[m] = *(const bf16x8*)((const char*)lds + row * 256 + (kb ^ ((row & 7) << 4)));
        }
        #pragma unroll
        for (int n = 0; n < 4; ++n) {
            int row = wc * 64 + n * 16 + colL;
            bfr[n] = *(const bf16x8*)((const char*)lds + 32768 + row * 256 + (kb ^ ((row & 7) << 4)));
        }
        #pragma unroll
        for (int m = 0; m < 4; ++m)
            #pragma unroll
            for (int n = 0; n < 4; ++n)
                acc[m][n] = __builtin_amdgcn_mfma_f32_16x16x32_bf16(af[m], bfr[n], acc[m][n], 0, 0, 0);
    }

    const float* bias = (ct == 0) ? bq : (ct == 1) ? bk : (ct == 2) ? bv : (ct == 3) ? bs : bqe;
    const float scale = (ct == 0) ? S1L : 1.f;
    const bool  is32 = (ct == 3);
    const int   hi = (ct == 2 || ct == 4) ? 1 : 0;
    u32* dstw = (ct == 3) ? (u32*)sk1 : ((ct == 1 || ct == 2) ? kv1 : qqe1);

    #pragma unroll
    for (int n = 0; n < 4; ++n) {
        const int c = wc * 64 + n * 16 + colL;
        const float bval = bias[c];
        #pragma unroll
        for (int m = 0; m < 4; ++m) {
            #pragma unroll
            for (int i = 0; i < 4; ++i) {
                const int r = rowbase + wr * 64 + m * 16 + kgrp * 4 + i;
                if (r < nN) {
                    float v = (acc[m][n][i] + bval) * scale;
                    if (is32) ((float*)dstw)[(size_t)r * 128 + c] = v;
                    else ((u16*)dstw)[(((size_t)r * 128 + c) << 1) + hi] = f2bf(v);
                }
            }
        }
    }
}

// ------------------------------------------- 128x128-tile MFMA GEMM, layer 2
__global__ __launch_bounds__(256) void k_lin_gemm2(
    const u16* __restrict__ hb, const u16* __restrict__ WB,
    const float* __restrict__ bq, const float* __restrict__ bk,
    const float* __restrict__ bv, const float* __restrict__ bs,
    const float* __restrict__ bqe,
    float* __restrict__ q2, u32* __restrict__ kv2, float* __restrict__ sk2,
    float* __restrict__ qe2, int nN)
{
    __shared__ __align__(16) u16 lds[2 * 128 * 128];
    const int tid = threadIdx.x;
    const int ct = blockIdx.y;
    const int rowbase = blockIdx.x * 128;

    {
        const int lr = tid >> 4, kc = tid & 15;
        #pragma unroll
        for (int it = 0; it < 8; ++it) {
            int row = it * 16 + lr;
            int grow = rowbase + row; if (grow >= nN) grow = nN - 1;
            uint4 va = *(const uint4*)(hb + (size_t)grow * 128 + kc * 8);
            *(uint4*)((char*)lds + row * 256 + ((kc * 16) ^ ((row & 7) << 4))) = va;
        }
        #pragma unroll
        for (int it = 0; it < 8; ++it) {
            int row = it * 16 + lr;
            uint4 vb = *(const uint4*)(WB + ((size_t)ct * 128 + row) * 128 + kc * 8);
            *(uint4*)((char*)lds + 32768 + row * 256 + ((kc * 16) ^ ((row & 7) << 4))) = vb;
        }
    }
    __syncthreads();

    const int wave = tid >> 6, lane = tid & 63;
    const int wr = wave >> 1, wc = wave & 1;
    const int colL = lane & 15, kgrp = lane >> 4;

    f32x4 acc[4][4];
    #pragma unroll
    for (int m = 0; m < 4; ++m)
        #pragma unroll
        for (int n = 0; n < 4; ++n) acc[m][n] = {0.f, 0.f, 0.f, 0.f};

    #pragma unroll
    for (int ks = 0; ks < 4; ++ks) {
        const int kb = ks * 64 + kgrp * 16;
        bf16x8 af[4], bfr[4];
        #pragma unroll
        for (int m = 0; m < 4; ++m) {
            int row = wr * 64 + m * 16 + colL;
            af[m] = *(const bf16x8*)((const char*)lds + row * 256 + (kb ^ ((row & 7) << 4)));
        }
        #pragma unroll
        for (int n = 0; n < 4; ++n) {
            int row = wc * 64 + n * 16 + colL;
            bfr[n] = *(const bf16x8*)((const char*)lds + 32768 + row * 256 + (kb ^ ((row & 7) << 4)));
        }
        #pragma unroll
        for (int m = 0; m < 4; ++m)
            #pragma unroll
            for (int n = 0; n < 4; ++n)
                acc[m][n] = __builtin_amdgcn_mfma_f32_16x16x32_bf16(af[m], bfr[n], acc[m][n], 0, 0, 0);
    }

    const int mode = ct * 2 + wc;   // 0:q2 1:kv2.lo 2:kv2.hi 3:sk2 4:qe2 5:dead
    if (mode == 5) return;

    #pragma unroll
    for (int n = 0; n < 4; ++n) {
        const int cl = n * 16 + colL;
        float bval;
        if (mode == 0) bval = bq[cl];
        else if (mode == 1) bval = bk[cl];
        else if (mode == 2) bval = bv[cl];
        else if (mode == 3) bval = bs[cl];
        else bval = (cl < 32) ? bqe[cl] : 0.f;
        #pragma unroll
        for (int m = 0; m < 4; ++m) {
            #pragma unroll
            for (int i = 0; i < 4; ++i) {
                const int r = rowbase + wr * 64 + m * 16 + kgrp * 4 + i;
                if (r < nN) {
                    const float v = acc[m][n][i] + bval;
                    if (mode == 0)      q2[(size_t)r * 64 + cl] = v * S2L;
                    else if (mode == 1) ((u16*)kv2)[(((size_t)r * 64 + cl) << 1)] = f2bf(v);
                    else if (mode == 2) ((u16*)kv2)[(((size_t)r * 64 + cl) << 1) + 1] = f2bf(v);
                    else if (mode == 3) sk2[(size_t)r * 64 + cl] = v;
                    else if (cl < 32)   qe2[(size_t)r * 32 + cl] = v;
                }
            }
        }
    }
}

// --------------------------- layer1 fused aggregation + finalize (h1b out)
__global__ __launch_bounds__(256) void k_agg1f(
    const int* __restrict__ rowptr, const int2* __restrict__ se,
    const u16* __restrict__ efc, const u32* __restrict__ qqe1,
    const u32* __restrict__ kv1, const float* __restrict__ sk1,
    const float* __restrict__ We, u16* __restrict__ h1b, int nN)
{
    __shared__ float Wes[32 * 128];   // 16 KB
    __shared__ float lsv[4][128];
    __shared__ float lsef[4][128];
    __shared__ float lden[4][4];
    const int tid = threadIdx.x;
    for (int i = tid; i < 1024; i += 256)
        ((float4*)Wes)[i] = ((const float4*)We)[i];
    __syncthreads();

    const int wave = tid >> 6, lane = tid & 63;
    const int d = blockIdx.x * 4 + wave;
    if (d >= nN) return;
    const int es = lane >> 5;
    const int h  = (lane >> 3) & 3;
    const int c8 = lane & 7;
    const int jb = h * 32 + c8 * 4;

    float den = 0.f;
    float4 sv = {0.f, 0.f, 0.f, 0.f}, sef = sv;
    {
        const uint4 qq = *(const uint4*)(qqe1 + (size_t)d * 128 + jb);
        const float4 qr  = {bflo(qq.x), bflo(qq.y), bflo(qq.z), bflo(qq.w)};
        const float4 qer = {bfhi(qq.x), bfhi(qq.y), bfhi(qq.z), bfhi(qq.w)};
        const int beg = rowptr[d], end = rowptr[d + 1];
        for (int cbeg = beg; cbeg < end; cbeg += 64) {
            const int cnt = min(64, end - cbeg);
            const int sreg = se[cbeg + (lane < cnt ? lane : cnt - 1)].x;
            #pragma unroll 2
            for (int t = 0; t < cnt; t += 2) {
                const int idx = t + es;
                const bool valid = idx < cnt;
                const int s = __shfl(sreg, idx);
                const int iec = cbeg + (valid ? idx : 0);
                const uint4 kp = *(const uint4*)(kv1 + ((u32)s << 7) + jb);
                const uint2 ee = *(const uint2*)(efc + ((size_t)iec << 5) + c8 * 4);
                const float f0 = bflo(ee.x), f1 = bfhi(ee.x);
                const float f2 = bflo(ee.y), f3 = bfhi(ee.y);
                float p = qr.x * bflo(kp.x) + qr.y * bflo(kp.y)
                        + qr.z * bflo(kp.z) + qr.w * bflo(kp.w)
                        + qer.x * f0 + qer.y * f1 + qer.z * f2 + qer.w * f3;
                p = dpp_add<0xB1>(p);
                p = dpp_add<0x4E>(p);
                p = dpp_add<0x141>(p);   // 8-lane total
                const float ex = valid ? exp2f(p) : 0.f;
                den += ex;
                sv.x += ex * bfhi(kp.x); sv.y += ex * bfhi(kp.y);
                sv.z += ex * bfhi(kp.z); sv.w += ex * bfhi(kp.w);
                sef.x += ex * f0; sef.y += ex * f1; sef.z += ex * f2; sef.w += ex * f3;
            }
        }
        den  += __shfl_xor(den, 32);
        sv.x += __shfl_xor(sv.x, 32); sv.y += __shfl_xor(sv.y, 32);
        sv.z += __shfl_xor(sv.z, 32); sv.w += __shfl_xor(sv.w, 32);
        sef.x += __shfl_xor(sef.x, 32); sef.y += __shfl_xor(sef.y, 32);
        sef.z += __shfl_xor(sef.z, 32); sef.w += __shfl_xor(sef.w, 32);
        if (es == 0) {
            *(float4*)&lsv[wave][jb]  = sv;
            *(float4*)&lsef[wave][jb] = sef;
            if (c8 == 0) lden[wave][h] = den;
        }
    }
    __builtin_amdgcn_wave_barrier();   // order wave-private LDS write->read
    {
        const int jA = lane, jB = lane + 64;
        const int hA = jA >> 5, hB = jB >> 5;
        const float ddA = lden[wave][hA], ddB = lden[wave][hB];
        const float invA = ddA > 0.f ? 1.0f / ddA : 0.f;
        const float invB = ddB > 0.f ? 1.0f / ddB : 0.f;
        float aA = lsv[wave][jA], aB = lsv[wave][jB];
        const float* spA = &lsef[wave][hA * 32];
        const float* spB = &lsef[wave][hB * 32];
        #pragma unroll
        for (int c = 0; c < 32; ++c) {
            aA = fmaf(spA[c], Wes[c * 128 + jA], aA);
            aB = fmaf(spB[c], Wes[c * 128 + jB], aB);
        }
        float oA = aA * invA + sk1[(size_t)d * 128 + jA];
        float oB = aB * invB + sk1[(size_t)d * 128 + jB];
        h1b[(size_t)d * 128 + jA] = f2bf(oA > 0.f ? oA : 0.f);
        h1b[(size_t)d * 128 + jB] = f2bf(oB > 0.f ? oB : 0.f);
    }
}

// --------------------------- layer2 fused aggregation + finalize (out)
__global__ __launch_bounds__(256) void k_agg2f(
    const int* __restrict__ rowptr, const int2* __restrict__ se,
    const u16* __restrict__ efc, const float* __restrict__ q2,
    const float* __restrict__ qe2, const u32* __restrict__ kv2,
    const float* __restrict__ sk2, const float* __restrict__ We,
    float* __restrict__ out, int nN)
{
    __shared__ float Wes[32 * 64];    // 8 KB
    __shared__ float lsv[4][64];
    __shared__ float lsef[4][32];
    __shared__ float lden[4];
    const int tid = threadIdx.x;
    for (int i = tid; i < 512; i += 256)
        ((float4*)Wes)[i] = ((const float4*)We)[i];
    __syncthreads();

    const int wave = tid >> 6, lane = tid & 63;
    const int d = blockIdx.x * 4 + wave;
    if (d >= nN) return;
    const int es  = lane >> 4;
    const int c16 = lane & 15;
    const int jb  = c16 * 4;
    const int ce  = (c16 & 7) * 4;

    float den = 0.f;
    float4 sv = {0.f, 0.f, 0.f, 0.f}, sef = sv;
    {
        const float4 qr = *(const float4*)(q2 + (size_t)d * 64 + jb);
        float4 qer = {0.f, 0.f, 0.f, 0.f};
        if (c16 < 8) qer = *(const float4*)(qe2 + (size_t)d * 32 + jb);
        const int beg = rowptr[d], end = rowptr[d + 1];
        for (int cbeg = beg; cbeg < end; cbeg += 64) {
            const int cnt = min(64, end - cbeg);
            const int sreg = se[cbeg + (lane < cnt ? lane : cnt - 1)].x;
            #pragma unroll 2
            for (int t = 0; t < cnt; t += 4) {
                const int idx = t + es;
                const bool valid = idx < cnt;
                const int s = __shfl(sreg, idx);
                const int iec = cbeg + (valid ? idx : 0);
                const uint4 kp = *(const uint4*)(kv2 + ((u32)s << 6) + jb);
                const uint2 ee = *(const uint2*)(efc + ((size_t)iec << 5) + ce);
                const float f0 = bflo(ee.x), f1 = bfhi(ee.x);
                const float f2 = bflo(ee.y), f3 = bfhi(ee.y);
                float p = qr.x * bflo(kp.x) + qr.y * bflo(kp.y)
                        + qr.z * bflo(kp.z) + qr.w * bflo(kp.w)
                        + qer.x * f0 + qer.y * f1 + qer.z * f2 + qer.w * f3;
                p = dpp_add<0xB1>(p);
                p = dpp_add<0x4E>(p);
                p = dpp_add<0x141>(p);
                p = dpp_add<0x140>(p);   // 16-lane total
                const float ex = valid ? exp2f(p) : 0.f;
                den += ex;
                sv.x += ex * bfhi(kp.x); sv.y += ex * bfhi(kp.y);
                sv.z += ex * bfhi(kp.z); sv.w += ex * bfhi(kp.w);
                sef.x += ex * f0; sef.y += ex * f1; sef.z += ex * f2; sef.w += ex * f3;
            }
        }
        #pragma unroll
        for (int m = 16; m <= 32; m <<= 1) {
            den  += __shfl_xor(den, m);
            sv.x += __shfl_xor(sv.x, m); sv.y += __shfl_xor(sv.y, m);
            sv.z += __shfl_xor(sv.z, m); sv.w += __shfl_xor(sv.w, m);
            sef.x += __shfl_xor(sef.x, m); sef.y += __shfl_xor(sef.y, m);
            sef.z += __shfl_xor(sef.z, m); sef.w += __shfl_xor(sef.w, m);
        }
        if (es == 0) {
            *(float4*)&lsv[wave][jb] = sv;
            if (c16 < 8) *(float4*)&lsef[wave][jb] = sef;
            if (c16 == 0) lden[wave] = den;
        }
    }
    __builtin_amdgcn_wave_barrier();
    {
        const float dd = lden[wave];
        const float inv = dd > 0.f ? 1.0f / dd : 0.f;
        float a = lsv[wave][lane];
        #pragma unroll
        for (int c = 0; c < 32; ++c) a = fmaf(lsef[wave][c], Wes[c * 64 + lane], a);
        out[(size_t)d * 64 + lane] = a * inv + sk2[(size_t)d * 64 + lane];
    }
}

// ---------------------------------------------------------------------------
extern "C" void kernel_launch(void* const* d_in, const int* in_sizes, int n_in,
                              void* d_out, int out_size, void* d_ws, size_t ws_size,
                              hipStream_t stream)
{
    const float* x   = (const float*)d_in[0];
    const int*   ei  = (const int*)d_in[1];
    const float* ef  = (const float*)d_in[2];
    const float* Wq1 = (const float*)d_in[3];  const float* bq1 = (const float*)d_in[4];
    const float* Wk1 = (const float*)d_in[5];  const float* bk1 = (const float*)d_in[6];
    const float* Wv1 = (const float*)d_in[7];  const float* bv1 = (const float*)d_in[8];
    const float* We1 = (const float*)d_in[9];
    const float* Ws1 = (const float*)d_in[10]; const float* bs1 = (const float*)d_in[11];
    const float* Wq2 = (const float*)d_in[12]; const float* bq2 = (const float*)d_in[13];
    const float* Wk2 = (const float*)d_in[14]; const float* bk2 = (const float*)d_in[15];
    const float* Wv2 = (const float*)d_in[16]; const float* bv2 = (const float*)d_in[17];
    const float* We2 = (const float*)d_in[18];
    const float* Ws2 = (const float*)d_in[19]; const float* bs2 = (const float*)d_in[20];

    const int nN = in_sizes[0] / 128;
    const int nE = in_sizes[1] / 2;
    const int* srcv = ei;
    const int* dstv = ei + nE;

    // ---- workspace layout (4-byte units) ----
    float* ws = (float*)d_ws;
    size_t off = 0;
    auto alloc = [&](size_t n) { float* p = ws + off; off += n; return p; };
    u32*   qqe1  = (u32*)alloc((size_t)nN * 128);
    float* sk1   = alloc((size_t)nN * 128);
    u32*   kv1   = (u32*)alloc((size_t)nN * 128);
    u16*   h1b   = (u16*)alloc((size_t)nN * 64);
    u16*   xb    = (u16*)alloc((size_t)nN * 64);
    u16*   efc   = (u16*)alloc((size_t)nE * 16);
    u16*   WB1   = (u16*)alloc(640 * 128 / 2);
    u16*   WB2   = (u16*)alloc(384 * 128 / 2);
    float* bqe1  = alloc(128);
    float* bqe2  = alloc(32);
    int* deg     = (int*)alloc(nN + 1024);   // deg[nN] + flags[1024], one memset
    int* flags   = deg + nN;
    int* partials= (int*)alloc(1024);
    int* rowptr  = (int*)alloc(nN + 1);
    int* fill    = (int*)alloc(nN);
    int2* se     = (int2*)alloc((size_t)nE * 2);
    // layer2 arrays (alias layer1 regions consumed before lin_gemm2 runs)
    float* l2 = (float*)qqe1;
    size_t o2 = 0;
    auto alloc2 = [&](size_t n) { float* p = l2 + o2; o2 += n; return p; };
    float* q2   = alloc2((size_t)nN * 64);
    u32*   kv2  = (u32*)alloc2((size_t)nN * 64);
    float* sk2  = alloc((size_t)nN * 64);
    float* qe2  = alloc((size_t)nN * 32);
    (void)ws_size; (void)n_in; (void)out_size;

    const int nChunk = (nN + 1023) / 1024;
    const int rowTiles = (nN + 127) / 128;
    const int aggBlocks = (nN + 3) / 4;

    // ---- CSR build ----
    hipMemsetAsync(deg, 0, (size_t)(nN + 1024) * sizeof(int), stream);
    k_hist<<<(nE + 255) / 256, 256, 0, stream>>>(dstv, deg, nE);
    k_scan_lb<<<nChunk, 1024, 0, stream>>>(deg, rowptr, fill, partials, flags,
                                           rowptr, nN, nE);

    // ---- scatter + prep (merged) ----
    long prepTotal = 65536L + 49152 + 16384 + 4096 + (long)nN * 32;
    long spTotal = (long)nE + prepTotal;
    k_scatter_prep<<<(int)((spTotal + 255) / 256), 256, 0, stream>>>(
        srcv, dstv, fill, se, nE,
        Wq1, Wk1, Wv1, Ws1, Wq2, Wk2, Wv2, Ws2, We1, We2, bq1, bq2,
        WB1, WB2, bqe1, bqe2, (const float4*)x, (uint2*)xb, nN);
    k_ef_gather<<<(nE * 4 + 255) / 256, 256, 0, stream>>>(
        se, (const float4*)ef, (uint4*)efc, nE);

    // ---- layer 1 ----
    k_lin_gemm1<<<dim3(rowTiles, 5), 256, 0, stream>>>(
        xb, WB1, bq1, bk1, bv1, bs1, bqe1, qqe1, kv1, sk1, nN);
    k_agg1f<<<aggBlocks, 256, 0, stream>>>(
        rowptr, se, efc, qqe1, kv1, sk1, We1, h1b, nN);

    // ---- layer 2 ----
    k_lin_gemm2<<<dim3(rowTiles, 3), 256, 0, stream>>>(
        h1b, WB2, bq2, bk2, bv2, bs2, bqe2, q2, kv2, sk2, qe2, nN);
    k_agg2f<<<aggBlocks, 256, 0, stream>>>(
        rowptr, se, efc, q2, qe2, kv2, sk2, We2, (float*)d_out, nN);
}

// Round 15
// 367.254 us; speedup vs baseline: 1.0319x; 1.0319x over previous
//
#include <hip/hip_runtime.h>
#include <hip/hip_bf16.h>

// GraphAttentionEmbedding: 2-layer TransformerConv GNN on MI355X.
// Round 15: revert to r13 (best: 370us) — 3-kernel scan chain restored
// (r14's decoupled-lookback spin was a regression). Keep r14's 4-thread/row
// ef_gather. Agg kernels at the measured random-gather/VALU floor
// (87us, 2.88TB/s L2-miss traffic, VALU 67%, stable across 3 rounds).

typedef unsigned int  u32;
typedef unsigned short u16;
typedef __attribute__((ext_vector_type(8))) __bf16 bf16x8;
typedef __attribute__((ext_vector_type(4))) float  f32x4;

#define S1L (0.17677669529663687f * 1.4426950408889634f)  // 1/sqrt(32)*log2(e)
#define S2L (0.125f * 1.4426950408889634f)                // 1/sqrt(64)*log2(e)

__device__ __forceinline__ u16 f2bf(float f) {
    u32 u = __float_as_uint(f);
    u32 r = (u + 0x7fffu + ((u >> 16) & 1u)) >> 16;   // round-nearest-even
    return (u16)r;
}
__device__ __forceinline__ float bflo(u32 u) { return __uint_as_float(u << 16); }
__device__ __forceinline__ float bfhi(u32 u) { return __uint_as_float(u & 0xffff0000u); }

template<int CTRL>
__device__ __forceinline__ float dpp_add(float x) {
    int y = __builtin_amdgcn_mov_dpp(__float_as_int(x), CTRL, 0xF, 0xF, true);
    return x + __int_as_float(y);
}

// ------------------------------------------------------------- CSR build
__global__ void k_hist(const int* __restrict__ dst, int* __restrict__ deg, int nE) {
    int e = blockIdx.x * 256 + threadIdx.x;
    if (e < nE) atomicAdd(&deg[dst[e]], 1);
}

__global__ __launch_bounds__(1024) void k_scan_part(const int* __restrict__ deg,
                                                    int* __restrict__ rp,
                                                    int* __restrict__ csum, int nN)
{
    __shared__ int buf[1024];
    const int tid = threadIdx.x, idx = blockIdx.x * 1024 + tid;
    int v = (idx < nN) ? deg[idx] : 0;
    buf[tid] = v;
    __syncthreads();
    for (int off = 1; off < 1024; off <<= 1) {
        int t = (tid >= off) ? buf[tid - off] : 0;
        __syncthreads();
        buf[tid] += t;
        __syncthreads();
    }
    if (idx < nN) rp[idx] = buf[tid] - v;
    if (tid == 1023) csum[blockIdx.x] = buf[1023];
}

__global__ __launch_bounds__(1024) void k_scan_tot(int* __restrict__ csum, int nb,
                                                   int* __restrict__ rowptr, int nN, int nE)
{
    __shared__ int buf[1024];
    const int tid = threadIdx.x;
    int v = (tid < nb) ? csum[tid] : 0;
    buf[tid] = v;
    __syncthreads();
    for (int off = 1; off < 1024; off <<= 1) {
        int t = (tid >= off) ? buf[tid - off] : 0;
        __syncthreads();
        buf[tid] += t;
        __syncthreads();
    }
    if (tid < nb) csum[tid] = buf[tid] - v;
    if (tid == 0) rowptr[nN] = nE;
}

__global__ void k_scan_apply(int* __restrict__ rp, const int* __restrict__ csum,
                             int* __restrict__ fill, int nN)
{
    int i = blockIdx.x * 256 + threadIdx.x;
    if (i < nN) { int r = rp[i] + csum[i >> 10]; rp[i] = r; fill[i] = r; }
}

// ------------- merged: permutation scatter + weight transposes + x->bf16
__global__ void k_scatter_prep(
    const int* __restrict__ src, const int* __restrict__ dst,
    int* __restrict__ fill, int2* __restrict__ se, int nE,
    const float* __restrict__ Wq1, const float* __restrict__ Wk1,
    const float* __restrict__ Wv1, const float* __restrict__ Ws1,
    const float* __restrict__ Wq2, const float* __restrict__ Wk2,
    const float* __restrict__ Wv2, const float* __restrict__ Ws2,
    const float* __restrict__ We1, const float* __restrict__ We2,
    const float* __restrict__ bq1, const float* __restrict__ bq2,
    u16* __restrict__ WB1, u16* __restrict__ WB2,
    float* __restrict__ bqe1, float* __restrict__ bqe2,
    const float4* __restrict__ x4, uint2* __restrict__ xb4, int nN)
{
    long g = (long)blockIdx.x * 256 + threadIdx.x;
    if (g < nE) {               // permutation scatter
        int e = (int)g;
        int p = atomicAdd(&fill[dst[e]], 1);
        se[p] = make_int2(src[e], e);
        return;
    }
    long t = g - nE;
    if (t < 65536) {            // WB1 main: 512 cols x 128 k
        int j = (int)t >> 7, k = (int)t & 127;
        int m = j >> 7, col = j & 127;
        const float* W = (m == 0) ? Wq1 : (m == 1) ? Wk1 : (m == 2) ? Wv1 : Ws1;
        WB1[t] = f2bf(W[k * 128 + col]);
        return;
    }
    t -= 65536;
    if (t < 49152) {            // WB2 main: 384 cols x 128 k (with pad)
        int j = (int)t >> 7, k = (int)t & 127;
        if (j < 256) {
            int m = j >> 6, col = j & 63;
            const float* W = (m == 0) ? Wq2 : (m == 1) ? Wk2 : (m == 2) ? Wv2 : Ws2;
            WB2[t] = f2bf(W[k * 64 + col]);
        } else if (j >= 288) {
            WB2[t] = 0;
        }
        return;
    }
    t -= 49152;
    if (t < 16384) {            // WqE1 -> WB1 cols 512..639
        int j = (int)t >> 7, m = (int)t & 127;
        int h = j >> 5, c = j & 31;
        float acc = 0.f;
        #pragma unroll
        for (int d = 0; d < 32; ++d)
            acc += Wq1[m * 128 + h * 32 + d] * We1[c * 128 + h * 32 + d];
        WB1[512 * 128 + j * 128 + m] = f2bf(acc * S1L);
        if (m == 0) {
            float b = 0.f;
            #pragma unroll
            for (int d = 0; d < 32; ++d)
                b += bq1[h * 32 + d] * We1[c * 128 + h * 32 + d];
            bqe1[j] = b * S1L;
        }
        return;
    }
    t -= 16384;
    if (t < 4096) {             // WqE2 -> WB2 cols 256..287
        int c = (int)t >> 7, m = (int)t & 127;
        float acc = 0.f;
        #pragma unroll
        for (int d = 0; d < 64; ++d)
            acc += Wq2[m * 64 + d] * We2[c * 64 + d];
        WB2[256 * 128 + c * 128 + m] = f2bf(acc * S2L);
        if (m == 0) {
            float b = 0.f;
            #pragma unroll
            for (int d = 0; d < 64; ++d) b += bq2[d] * We2[c * 64 + d];
            bqe2[c] = b * S2L;
        }
        return;
    }
    t -= 4096;
    if (t < (long)nN * 32) {    // x -> bf16
        float4 f = x4[t];
        xb4[t] = make_uint2((u32)f2bf(f.x) | ((u32)f2bf(f.y) << 16),
                            (u32)f2bf(f.z) | ((u32)f2bf(f.w) << 16));
    }
}

// gather+convert edge features into CSR order; 4 threads/row, uint4 writes
__global__ void k_ef_gather(const int2* __restrict__ se, const float4* __restrict__ ef4,
                            uint4* __restrict__ efc4, int nE)
{
    int t = blockIdx.x * 256 + threadIdx.x;
    int p = t >> 2, sub = t & 3;
    if (p >= nE) return;
    int e = se[p].y;
    float4 a = ef4[(size_t)e * 8 + sub * 2];
    float4 b = ef4[(size_t)e * 8 + sub * 2 + 1];
    efc4[(size_t)p * 4 + sub] =
        make_uint4((u32)f2bf(a.x) | ((u32)f2bf(a.y) << 16),
                   (u32)f2bf(a.z) | ((u32)f2bf(a.w) << 16),
                   (u32)f2bf(b.x) | ((u32)f2bf(b.y) << 16),
                   (u32)f2bf(b.z) | ((u32)f2bf(b.w) << 16));
}

// ------------------------------------------- 128x128-tile MFMA GEMM, layer 1
__global__ __launch_bounds__(256) void k_lin_gemm1(
    const u16* __restrict__ xb, const u16* __restrict__ WB,
    const float* __restrict__ bq, const float* __restrict__ bk,
    const float* __restrict__ bv, const float* __restrict__ bs,
    const float* __restrict__ bqe,
    u32* __restrict__ qqe1, u32* __restrict__ kv1, float* __restrict__ sk1, int nN)
{
    __shared__ __align__(16) u16 lds[2 * 128 * 128];   // 64 KB
    const int tid = threadIdx.x;
    const int ct = blockIdx.y;
    const int rowbase = blockIdx.x * 128;

    {
        const int lr = tid >> 4, kc = tid & 15;
        #pragma unroll
        for (int it = 0; it < 8; ++it) {
            int row = it * 16 + lr;
            int grow = rowbase + row; if (grow >= nN) grow = nN - 1;
            uint4 va = *(const uint4*)(xb + (size_t)grow * 128 + kc * 8);
            *(uint4*)((char*)lds + row * 256 + ((kc * 16) ^ ((row & 7) << 4))) = va;
        }
        #pragma unroll
        for (int it = 0; it < 8; ++it) {
            int row = it * 16 + lr;
            uint4 vb = *(const uint4*)(WB + ((size_t)ct * 128 + row) * 128 + kc * 8);
            *(uint4*)((char*)lds + 32768 + row * 256 + ((kc * 16) ^ ((row & 7) << 4))) = vb;
        }
    }
    __syncthreads();

    const int wave = tid >> 6, lane = tid & 63;
    const int wr = wave >> 1, wc = wave & 1;
    const int colL = lane & 15, kgrp = lane >> 4;

    f32x4 acc[4][4];
    #pragma unroll
    for (int m = 0; m < 4; ++m)
        #pragma unroll
        for (int n = 0; n < 4; ++n) acc[m][n] = {0.f, 0.f, 0.f, 0.f};

    #pragma unroll
    for (int ks = 0; ks < 4; ++ks) {
        const int kb = ks * 64 + kgrp * 16;
        bf16x8 af[4], bfr[4];
        #pragma unroll
        for (int m = 0; m < 4; ++m) {
            int row = wr * 64 + m * 16 + colL;
            af[m] = *(const bf16x8*)((const char*)lds + row * 256 + (kb ^ ((row & 7) << 4)));
        }
        #pragma unroll
        for (int n = 0; n < 4; ++n) {
            int row = wc * 64 + n * 16 + colL;
            bfr[n] = *(const bf16x8*)((const char*)lds + 32768 + row * 256 + (kb ^ ((row & 7) << 4)));
        }
        #pragma unroll
        for (int m = 0; m < 4; ++m)
            #pragma unroll
            for (int n = 0; n < 4; ++n)
                acc[m][n] = __builtin_amdgcn_mfma_f32_16x16x32_bf16(af[m], bfr[n], acc[m][n], 0, 0, 0);
    }

    const float* bias = (ct == 0) ? bq : (ct == 1) ? bk : (ct == 2) ? bv : (ct == 3) ? bs : bqe;
    const float scale = (ct == 0) ? S1L : 1.f;
    const bool  is32 = (ct == 3);
    const int   hi = (ct == 2 || ct == 4) ? 1 : 0;
    u32* dstw = (ct == 3) ? (u32*)sk1 : ((ct == 1 || ct == 2) ? kv1 : qqe1);

    #pragma unroll
    for (int n = 0; n < 4; ++n) {
        const int c = wc * 64 + n * 16 + colL;
        const float bval = bias[c];
        #pragma unroll
        for (int m = 0; m < 4; ++m) {
            #pragma unroll
            for (int i = 0; i < 4; ++i) {
                const int r = rowbase + wr * 64 + m * 16 + kgrp * 4 + i;
                if (r < nN) {
                    float v = (acc[m][n][i] + bval) * scale;
                    if (is32) ((float*)dstw)[(size_t)r * 128 + c] = v;
                    else ((u16*)dstw)[(((size_t)r * 128 + c) << 1) + hi] = f2bf(v);
                }
            }
        }
    }
}

// ------------------------------------------- 128x128-tile MFMA GEMM, layer 2
__global__ __launch_bounds__(256) void k_lin_gemm2(
    const u16* __restrict__ hb, const u16* __restrict__ WB,
    const float* __restrict__ bq, const float* __restrict__ bk,
    const float* __restrict__ bv, const float* __restrict__ bs,
    const float* __restrict__ bqe,
    float* __restrict__ q2, u32* __restrict__ kv2, float* __restrict__ sk2,
    float* __restrict__ qe2, int nN)
{
    __shared__ __align__(16) u16 lds[2 * 128 * 128];
    const int tid = threadIdx.x;
    const int ct = blockIdx.y;
    const int rowbase = blockIdx.x * 128;

    {
        const int lr = tid >> 4, kc = tid & 15;
        #pragma unroll
        for (int it = 0; it < 8; ++it) {
            int row = it * 16 + lr;
            int grow = rowbase + row; if (grow >= nN) grow = nN - 1;
            uint4 va = *(const uint4*)(hb + (size_t)grow * 128 + kc * 8);
            *(uint4*)((char*)lds + row * 256 + ((kc * 16) ^ ((row & 7) << 4))) = va;
        }
        #pragma unroll
        for (int it = 0; it < 8; ++it) {
            int row = it * 16 + lr;
            uint4 vb = *(const uint4*)(WB + ((size_t)ct * 128 + row) * 128 + kc * 8);
            *(uint4*)((char*)lds + 32768 + row * 256 + ((kc * 16) ^ ((row & 7) << 4))) = vb;
        }
    }
    __syncthreads();

    const int wave = tid >> 6, lane = tid & 63;
    const int wr = wave >> 1, wc = wave & 1;
    const int colL = lane & 15, kgrp = lane >> 4;

    f32x4 acc[4][4];
    #pragma unroll
    for (int m = 0; m < 4; ++m)
        #pragma unroll
        for (int n = 0; n < 4; ++n) acc[m][n] = {0.f, 0.f, 0.f, 0.f};

    #pragma unroll
    for (int ks = 0; ks < 4; ++ks) {
        const int kb = ks * 64 + kgrp * 16;
        bf16x8 af[4], bfr[4];
        #pragma unroll
        for (int m = 0; m < 4; ++m) {
            int row = wr * 64 + m * 16 + colL;
            af[m] = *(const bf16x8*)((const char*)lds + row * 256 + (kb ^ ((row & 7) << 4)));
        }
        #pragma unroll
        for (int n = 0; n < 4; ++n) {
            int row = wc * 64 + n * 16 + colL;
            bfr[n] = *(const bf16x8*)((const char*)lds + 32768 + row * 256 + (kb ^ ((row & 7) << 4)));
        }
        #pragma unroll
        for (int m = 0; m < 4; ++m)
            #pragma unroll
            for (int n = 0; n < 4; ++n)
                acc[m][n] = __builtin_amdgcn_mfma_f32_16x16x32_bf16(af[m], bfr[n], acc[m][n], 0, 0, 0);
    }

    const int mode = ct * 2 + wc;   // 0:q2 1:kv2.lo 2:kv2.hi 3:sk2 4:qe2 5:dead
    if (mode == 5) return;

    #pragma unroll
    for (int n = 0; n < 4; ++n) {
        const int cl = n * 16 + colL;
        float bval;
        if (mode == 0) bval = bq[cl];
        else if (mode == 1) bval = bk[cl];
        else if (mode == 2) bval = bv[cl];
        else if (mode == 3) bval = bs[cl];
        else bval = (cl < 32) ? bqe[cl] : 0.f;
        #pragma unroll
        for (int m = 0; m < 4; ++m) {
            #pragma unroll
            for (int i = 0; i < 4; ++i) {
                const int r = rowbase + wr * 64 + m * 16 + kgrp * 4 + i;
                if (r < nN) {
                    const float v = acc[m][n][i] + bval;
                    if (mode == 0)      q2[(size_t)r * 64 + cl] = v * S2L;
                    else if (mode == 1) ((u16*)kv2)[(((size_t)r * 64 + cl) << 1)] = f2bf(v);
                    else if (mode == 2) ((u16*)kv2)[(((size_t)r * 64 + cl) << 1) + 1] = f2bf(v);
                    else if (mode == 3) sk2[(size_t)r * 64 + cl] = v;
                    else if (cl < 32)   qe2[(size_t)r * 32 + cl] = v;
                }
            }
        }
    }
}

// --------------------------- layer1 fused aggregation + finalize (h1b out)
__global__ __launch_bounds__(256) void k_agg1f(
    const int* __restrict__ rowptr, const int2* __restrict__ se,
    const u16* __restrict__ efc, const u32* __restrict__ qqe1,
    const u32* __restrict__ kv1, const float* __restrict__ sk1,
    const float* __restrict__ We, u16* __restrict__ h1b, int nN)
{
    __shared__ float Wes[32 * 128];   // 16 KB
    __shared__ float lsv[4][128];
    __shared__ float lsef[4][128];
    __shared__ float lden[4][4];
    const int tid = threadIdx.x;
    for (int i = tid; i < 1024; i += 256)
        ((float4*)Wes)[i] = ((const float4*)We)[i];
    __syncthreads();

    const int wave = tid >> 6, lane = tid & 63;
    const int d = blockIdx.x * 4 + wave;
    if (d >= nN) return;
    const int es = lane >> 5;
    const int h  = (lane >> 3) & 3;
    const int c8 = lane & 7;
    const int jb = h * 32 + c8 * 4;

    float den = 0.f;
    float4 sv = {0.f, 0.f, 0.f, 0.f}, sef = sv;
    {
        const uint4 qq = *(const uint4*)(qqe1 + (size_t)d * 128 + jb);
        const float4 qr  = {bflo(qq.x), bflo(qq.y), bflo(qq.z), bflo(qq.w)};
        const float4 qer = {bfhi(qq.x), bfhi(qq.y), bfhi(qq.z), bfhi(qq.w)};
        const int beg = rowptr[d], end = rowptr[d + 1];
        for (int cbeg = beg; cbeg < end; cbeg += 64) {
            const int cnt = min(64, end - cbeg);
            const int sreg = se[cbeg + (lane < cnt ? lane : cnt - 1)].x;
            #pragma unroll 2
            for (int t = 0; t < cnt; t += 2) {
                const int idx = t + es;
                const bool valid = idx < cnt;
                const int s = __shfl(sreg, idx);
                const int iec = cbeg + (valid ? idx : 0);
                const uint4 kp = *(const uint4*)(kv1 + ((u32)s << 7) + jb);
                const uint2 ee = *(const uint2*)(efc + ((size_t)iec << 5) + c8 * 4);
                const float f0 = bflo(ee.x), f1 = bfhi(ee.x);
                const float f2 = bflo(ee.y), f3 = bfhi(ee.y);
                float p = qr.x * bflo(kp.x) + qr.y * bflo(kp.y)
                        + qr.z * bflo(kp.z) + qr.w * bflo(kp.w)
                        + qer.x * f0 + qer.y * f1 + qer.z * f2 + qer.w * f3;
                p = dpp_add<0xB1>(p);
                p = dpp_add<0x4E>(p);
                p = dpp_add<0x141>(p);   // 8-lane total
                const float ex = valid ? exp2f(p) : 0.f;
                den += ex;
                sv.x += ex * bfhi(kp.x); sv.y += ex * bfhi(kp.y);
                sv.z += ex * bfhi(kp.z); sv.w += ex * bfhi(kp.w);
                sef.x += ex * f0; sef.y += ex * f1; sef.z += ex * f2; sef.w += ex * f3;
            }
        }
        den  += __shfl_xor(den, 32);
        sv.x += __shfl_xor(sv.x, 32); sv.y += __shfl_xor(sv.y, 32);
        sv.z += __shfl_xor(sv.z, 32); sv.w += __shfl_xor(sv.w, 32);
        sef.x += __shfl_xor(sef.x, 32); sef.y += __shfl_xor(sef.y, 32);
        sef.z += __shfl_xor(sef.z, 32); sef.w += __shfl_xor(sef.w, 32);
        if (es == 0) {
            *(float4*)&lsv[wave][jb]  = sv;
            *(float4*)&lsef[wave][jb] = sef;
            if (c8 == 0) lden[wave][h] = den;
        }
    }
    __builtin_amdgcn_wave_barrier();   // order wave-private LDS write->read
    {
        const int jA = lane, jB = lane + 64;
        const int hA = jA >> 5, hB = jB >> 5;
        const float ddA = lden[wave][hA], ddB = lden[wave][hB];
        const float invA = ddA > 0.f ? 1.0f / ddA : 0.f;
        const float invB = ddB > 0.f ? 1.0f / ddB : 0.f;
        float aA = lsv[wave][jA], aB = lsv[wave][jB];
        const float* spA = &lsef[wave][hA * 32];
        const float* spB = &lsef[wave][hB * 32];
        #pragma unroll
        for (int c = 0; c < 32; ++c) {
            aA = fmaf(spA[c], Wes[c * 128 + jA], aA);
            aB = fmaf(spB[c], Wes[c * 128 + jB], aB);
        }
        float oA = aA * invA + sk1[(size_t)d * 128 + jA];
        float oB = aB * invB + sk1[(size_t)d * 128 + jB];
        h1b[(size_t)d * 128 + jA] = f2bf(oA > 0.f ? oA : 0.f);
        h1b[(size_t)d * 128 + jB] = f2bf(oB > 0.f ? oB : 0.f);
    }
}

// --------------------------- layer2 fused aggregation + finalize (out)
__global__ __launch_bounds__(256) void k_agg2f(
    const int* __restrict__ rowptr, const int2* __restrict__ se,
    const u16* __restrict__ efc, const float* __restrict__ q2,
    const float* __restrict__ qe2, const u32* __restrict__ kv2,
    const float* __restrict__ sk2, const float* __restrict__ We,
    float* __restrict__ out, int nN)
{
    __shared__ float Wes[32 * 64];    // 8 KB
    __shared__ float lsv[4][64];
    __shared__ float lsef[4][32];
    __shared__ float lden[4];
    const int tid = threadIdx.x;
    for (int i = tid; i < 512; i += 256)
        ((float4*)Wes)[i] = ((const float4*)We)[i];
    __syncthreads();

    const int wave = tid >> 6, lane = tid & 63;
    const int d = blockIdx.x * 4 + wave;
    if (d >= nN) return;
    const int es  = lane >> 4;
    const int c16 = lane & 15;
    const int jb  = c16 * 4;
    const int ce  = (c16 & 7) * 4;

    float den = 0.f;
    float4 sv = {0.f, 0.f, 0.f, 0.f}, sef = sv;
    {
        const float4 qr = *(const float4*)(q2 + (size_t)d * 64 + jb);
        float4 qer = {0.f, 0.f, 0.f, 0.f};
        if (c16 < 8) qer = *(const float4*)(qe2 + (size_t)d * 32 + jb);
        const int beg = rowptr[d], end = rowptr[d + 1];
        for (int cbeg = beg; cbeg < end; cbeg += 64) {
            const int cnt = min(64, end - cbeg);
            const int sreg = se[cbeg + (lane < cnt ? lane : cnt - 1)].x;
            #pragma unroll 2
            for (int t = 0; t < cnt; t += 4) {
                const int idx = t + es;
                const bool valid = idx < cnt;
                const int s = __shfl(sreg, idx);
                const int iec = cbeg + (valid ? idx : 0);
                const uint4 kp = *(const uint4*)(kv2 + ((u32)s << 6) + jb);
                const uint2 ee = *(const uint2*)(efc + ((size_t)iec << 5) + ce);
                const float f0 = bflo(ee.x), f1 = bfhi(ee.x);
                const float f2 = bflo(ee.y), f3 = bfhi(ee.y);
                float p = qr.x * bflo(kp.x) + qr.y * bflo(kp.y)
                        + qr.z * bflo(kp.z) + qr.w * bflo(kp.w)
                        + qer.x * f0 + qer.y * f1 + qer.z * f2 + qer.w * f3;
                p = dpp_add<0xB1>(p);
                p = dpp_add<0x4E>(p);
                p = dpp_add<0x141>(p);
                p = dpp_add<0x140>(p);   // 16-lane total
                const float ex = valid ? exp2f(p) : 0.f;
                den += ex;
                sv.x += ex * bfhi(kp.x); sv.y += ex * bfhi(kp.y);
                sv.z += ex * bfhi(kp.z); sv.w += ex * bfhi(kp.w);
                sef.x += ex * f0; sef.y += ex * f1; sef.z += ex * f2; sef.w += ex * f3;
            }
        }
        #pragma unroll
        for (int m = 16; m <= 32; m <<= 1) {
            den  += __shfl_xor(den, m);
            sv.x += __shfl_xor(sv.x, m); sv.y += __shfl_xor(sv.y, m);
            sv.z += __shfl_xor(sv.z, m); sv.w += __shfl_xor(sv.w, m);
            sef.x += __shfl_xor(sef.x, m); sef.y += __shfl_xor(sef.y, m);
            sef.z += __shfl_xor(sef.z, m); sef.w += __shfl_xor(sef.w, m);
        }
        if (es == 0) {
            *(float4*)&lsv[wave][jb] = sv;
            if (c16 < 8) *(float4*)&lsef[wave][jb] = sef;
            if (c16 == 0) lden[wave] = den;
        }
    }
    __builtin_amdgcn_wave_barrier();
    {
        const float dd = lden[wave];
        const float inv = dd > 0.f ? 1.0f / dd : 0.f;
        float a = lsv[wave][lane];
        #pragma unroll
        for (int c = 0; c < 32; ++c) a = fmaf(lsef[wave][c], Wes[c * 64 + lane], a);
        out[(size_t)d * 64 + lane] = a * inv + sk2[(size_t)d * 64 + lane];
    }
}

// ---------------------------------------------------------------------------
extern "C" void kernel_launch(void* const* d_in, const int* in_sizes, int n_in,
                              void* d_out, int out_size, void* d_ws, size_t ws_size,
                              hipStream_t stream)
{
    const float* x   = (const float*)d_in[0];
    const int*   ei  = (const int*)d_in[1];
    const float* ef  = (const float*)d_in[2];
    const float* Wq1 = (const float*)d_in[3];  const float* bq1 = (const float*)d_in[4];
    const float* Wk1 = (const float*)d_in[5];  const float* bk1 = (const float*)d_in[6];
    const float* Wv1 = (const float*)d_in[7];  const float* bv1 = (const float*)d_in[8];
    const float* We1 = (const float*)d_in[9];
    const float* Ws1 = (const float*)d_in[10]; const float* bs1 = (const float*)d_in[11];
    const float* Wq2 = (const float*)d_in[12]; const float* bq2 = (const float*)d_in[13];
    const float* Wk2 = (const float*)d_in[14]; const float* bk2 = (const float*)d_in[15];
    const float* Wv2 = (const float*)d_in[16]; const float* bv2 = (const float*)d_in[17];
    const float* We2 = (const float*)d_in[18];
    const float* Ws2 = (const float*)d_in[19]; const float* bs2 = (const float*)d_in[20];

    const int nN = in_sizes[0] / 128;
    const int nE = in_sizes[1] / 2;
    const int* srcv = ei;
    const int* dstv = ei + nE;

    // ---- workspace layout (4-byte units) ----
    float* ws = (float*)d_ws;
    size_t off = 0;
    auto alloc = [&](size_t n) { float* p = ws + off; off += n; return p; };
    u32*   qqe1  = (u32*)alloc((size_t)nN * 128);
    float* sk1   = alloc((size_t)nN * 128);
    u32*   kv1   = (u32*)alloc((size_t)nN * 128);
    u16*   h1b   = (u16*)alloc((size_t)nN * 64);
    u16*   xb    = (u16*)alloc((size_t)nN * 64);
    u16*   efc   = (u16*)alloc((size_t)nE * 16);
    u16*   WB1   = (u16*)alloc(640 * 128 / 2);
    u16*   WB2   = (u16*)alloc(384 * 128 / 2);
    float* bqe1  = alloc(128);
    float* bqe2  = alloc(32);
    int* deg     = (int*)alloc(nN);
    int* rowptr  = (int*)alloc(nN + 1);
    int* fill    = (int*)alloc(nN);
    int* csum    = (int*)alloc(1024);
    int2* se     = (int2*)alloc((size_t)nE * 2);
    // layer2 arrays (alias layer1 regions consumed before lin_gemm2 runs)
    float* l2 = (float*)qqe1;
    size_t o2 = 0;
    auto alloc2 = [&](size_t n) { float* p = l2 + o2; o2 += n; return p; };
    float* q2   = alloc2((size_t)nN * 64);
    u32*   kv2  = (u32*)alloc2((size_t)nN * 64);
    float* sk2  = alloc((size_t)nN * 64);
    float* qe2  = alloc((size_t)nN * 32);
    (void)ws_size; (void)n_in; (void)out_size;

    const int nChunk = (nN + 1023) / 1024;
    const int rowTiles = (nN + 127) / 128;
    const int aggBlocks = (nN + 3) / 4;

    // ---- CSR build ----
    hipMemsetAsync(deg, 0, (size_t)nN * sizeof(int), stream);
    k_hist<<<(nE + 255) / 256, 256, 0, stream>>>(dstv, deg, nE);
    k_scan_part<<<nChunk, 1024, 0, stream>>>(deg, rowptr, csum, nN);
    k_scan_tot<<<1, 1024, 0, stream>>>(csum, nChunk, rowptr, nN, nE);
    k_scan_apply<<<(nN + 255) / 256, 256, 0, stream>>>(rowptr, csum, fill, nN);

    // ---- scatter + prep (merged) ----
    long prepTotal = 65536L + 49152 + 16384 + 4096 + (long)nN * 32;
    long spTotal = (long)nE + prepTotal;
    k_scatter_prep<<<(int)((spTotal + 255) / 256), 256, 0, stream>>>(
        srcv, dstv, fill, se, nE,
        Wq1, Wk1, Wv1, Ws1, Wq2, Wk2, Wv2, Ws2, We1, We2, bq1, bq2,
        WB1, WB2, bqe1, bqe2, (const float4*)x, (uint2*)xb, nN);
    k_ef_gather<<<(nE * 4 + 255) / 256, 256, 0, stream>>>(
        se, (const float4*)ef, (uint4*)efc, nE);

    // ---- layer 1 ----
    k_lin_gemm1<<<dim3(rowTiles, 5), 256, 0, stream>>>(
        xb, WB1, bq1, bk1, bv1, bs1, bqe1, qqe1, kv1, sk1, nN);
    k_agg1f<<<aggBlocks, 256, 0, stream>>>(
        rowptr, se, efc, qqe1, kv1, sk1, We1, h1b, nN);

    // ---- layer 2 ----
    k_lin_gemm2<<<dim3(rowTiles, 3), 256, 0, stream>>>(
        h1b, WB2, bq2, bk2, bv2, bs2, bqe2, q2, kv2, sk2, qe2, nN);
    k_agg2f<<<aggBlocks, 256, 0, stream>>>(
        rowptr, se, efc, q2, qe2, kv2, sk2, We2, (float*)d_out, nN);
}